// Round 6
// baseline (597.009 us; speedup 1.0000x reference)
//
#include <hip/hip_runtime.h>

#define BB 128
#define TT 1024
#define VV 192
#define NTHREADS 256
#define NWAVES 4
#define LN2 0.69314718055994530942f

typedef float floatx2 __attribute__((ext_vector_type(2)));
typedef float floatx4 __attribute__((ext_vector_type(4)));

__device__ __forceinline__ unsigned short f32_to_bf16(float f) {
    unsigned int u = __float_as_uint(f);
    u += 0x7fffu + ((u >> 16) & 1u);
    return (unsigned short)(u >> 16);
}
__device__ __forceinline__ float bf8_to_f32(unsigned char h) {
    floatx2 v = __builtin_amdgcn_cvt_pk_f32_bf8((int)(unsigned int)h, false);
    return v.x;
}
__device__ __forceinline__ unsigned char f32_to_bf8(float f) {
    int pk = __builtin_amdgcn_cvt_pk_bf8_f32(f, f, 0, false);
    return (unsigned char)(pk & 0xff);
}
__device__ __forceinline__ unsigned char f32_to_fp8(float f) {
    int pk = __builtin_amdgcn_cvt_pk_fp8_f32(f, f, 0, false);
    return (unsigned char)(pk & 0xff);
}

// LDS-only barrier: does NOT drain vmcnt (prefetch loads stay in flight)
#define LBAR() __asm__ volatile("s_waitcnt lgkmcnt(0)\n\ts_barrier" ::: "memory")

__launch_bounds__(NTHREADS, 1)
__global__ void crf_kernel(const float* __restrict__ emissions,
                           const int* __restrict__ tags,
                           const int* __restrict__ mask,
                           const float* __restrict__ trans,
                           const float* __restrict__ start_trans,
                           const float* __restrict__ end_trans,
                           float* __restrict__ out)
{
    const int b = blockIdx.x;
    const int tid = threadIdx.x;
    const int lane = tid & 63;
    const int wid = tid >> 6;        // 0..3
    const int quad = lane >> 4;      // 0..3
    const int col = lane & 15;       // 0..15

    // Q state in fp8-e5m2 bytes, double-buffered
    __shared__ __align__(16) unsigned char qb8[2][VV];
    __shared__ int smask[TT];
    __shared__ float wred[NWAVES];
    __shared__ float wg[NWAVES];
    __shared__ int   wsl[NWAVES];
    __shared__ float sh_logden;

    const float* em_b = emissions + (size_t)b * TT * VV;
    const int* mask_b = mask + b * TT;

    // this lane's epilogue column (quads 0..2 own one column each; quad 3 dups quad 0)
    const int nl = wid * 48 + (quad < 3 ? quad : 0) * 16 + col;

    // ---- E fragments as fp8-e4m3 packed i64: 6 K-tiles x 3 N-tiles ----
    // B layout (16x16x32 fp8): n = lane&15, k = quad*8 + j (byte j of the i64)
    long ef8[18];
    #pragma unroll
    for (int kt = 0; kt < 6; ++kt) {
        #pragma unroll
        for (int h = 0; h < 3; ++h) {
            const int kb = kt * 32 + quad * 8;
            const int n = wid * 48 + h * 16 + col;
            unsigned long long v = 0;
            #pragma unroll
            for (int j = 0; j < 8; ++j) {
                float x = __expf(trans[(kb + j) * VV + n]);
                v |= (unsigned long long)f32_to_fp8(x) << (8 * j);
            }
            ef8[kt * 3 + h] = (long)v;
        }
    }

    // ---- preload mask into LDS ----
    for (int t = tid; t < TT; t += NTHREADS) smask[t] = mask_b[t];

    // ---- emission registers: pexp rows for THIS lane's column nl ----
    float emA[8], emB[8];
    #pragma unroll
    for (int r = 0; r < 8; ++r) emA[r] = __expf(em_b[(size_t)r * VV + nl]);
    #pragma unroll
    for (int r = 0; r < 8; ++r) emB[r] = __expf(em_b[(size_t)(8 + r) * VV + nl]);

    // ---- init Q0 ----
    if (tid < VV) {
        float a0 = start_trans[tid] + em_b[tid];
        qb8[0][tid] = f32_to_bf8(fminf(__expf(a0), 28672.f));
    }
    float carry2 = 0.f;
    int cur = 0;
    __syncthreads();

    // one CRF step t: consumes qb8[cur]; pe = exp(em[t][nl]) in a register
    auto dostep = [&](int t, float pe) {
        const unsigned char* qc = qb8[cur];
        long a8[6];
        #pragma unroll
        for (int kt = 0; kt < 6; ++kt)
            a8[kt] = *(const long*)(qc + kt * 32 + quad * 8);
        float q0 = bf8_to_f32(qc[0]);
        unsigned char prevb = qc[nl];
        int mk = smask[t];

        floatx4 acc[3];
        #pragma unroll
        for (int h = 0; h < 3; ++h) acc[h] = (floatx4){0.f, 0.f, 0.f, 0.f};
        #pragma unroll
        for (int kt = 0; kt < 6; ++kt) {
            #pragma unroll
            for (int h = 0; h < 3; ++h)
                acc[h] = __builtin_amdgcn_mfma_f32_16x16x32_bf8_fp8(
                             a8[kt], ef8[kt * 3 + h], acc[h], 0, 0, 0);
        }

        float r = __builtin_amdgcn_rcpf(q0);
        carry2 += mk ? __log2f(q0) : 0.f;

        if (quad < 3) {
            float qn = fminf(acc[quad][0] * pe * r, 28672.f);
            unsigned char nb = mk ? f32_to_bf8(qn) : prevb;
            qb8[cur ^ 1][nl] = nb;
        }
        LBAR();
        cur ^= 1;
    };

    // ---- main loop: 16-step bodies; emA/emB refilled right after last use ----
    for (int t0 = 0; t0 < TT; t0 += 16) {
        if (t0 > 0) dostep(t0 + 0, emA[0]);
        dostep(t0 + 1, emA[1]);
        dostep(t0 + 2, emA[2]);
        dostep(t0 + 3, emA[3]);
        dostep(t0 + 4, emA[4]);
        dostep(t0 + 5, emA[5]);
        dostep(t0 + 6, emA[6]);
        dostep(t0 + 7, emA[7]);
        // refill emA <- rows [t0+16, t0+24)  (first use 8 steps away)
        {
            #pragma unroll
            for (int r = 0; r < 8; ++r) {
                int rr = t0 + 16 + r; rr = rr < TT ? rr : TT - 1;
                emA[r] = __expf(em_b[(size_t)rr * VV + nl]);
            }
        }
        dostep(t0 + 8,  emB[0]);
        dostep(t0 + 9,  emB[1]);
        dostep(t0 + 10, emB[2]);
        dostep(t0 + 11, emB[3]);
        dostep(t0 + 12, emB[4]);
        dostep(t0 + 13, emB[5]);
        dostep(t0 + 14, emB[6]);
        dostep(t0 + 15, emB[7]);
        // refill emB <- rows [t0+24, t0+32)
        {
            #pragma unroll
            for (int r = 0; r < 8; ++r) {
                int rr = t0 + 24 + r; rr = rr < TT ? rr : TT - 1;
                emB[r] = __expf(em_b[(size_t)rr * VV + nl]);
            }
        }
    }

    // ---- final lse: logden = ln2*carry2 + log(sum_j Q[j]*exp(end[j])) ----
    float v = 0.f;
    if (tid < VV) v = bf8_to_f32(qb8[cur][tid]) * __expf(end_trans[tid]);
    #pragma unroll
    for (int off = 1; off < 64; off <<= 1)
        v += __shfl_xor(v, off);
    if (lane == 0) wred[wid] = v;
    __syncthreads();
    if (tid == 0) {
        float ssum = 0.f;
        for (int w = 0; w < NWAVES; ++w) ssum += wred[w];
        sh_logden = LN2 * carry2 + __logf(ssum + 1e-8f);
    }

    // ---- gold score + seq_len (strided over t) ----
    float gp = 0.f;
    int sl = 0;
    for (int t = tid; t < TT; t += NTHREADS) {
        sl += smask[t];
        if (t >= 1) {
            int tg  = tags[b * TT + t];
            int tgp = tags[b * TT + t - 1];
            float term = em_b[(size_t)t * VV + tg] + trans[tgp * VV + tg];
            gp += smask[t] ? term : 0.f;
        }
    }
    #pragma unroll
    for (int off = 1; off < 64; off <<= 1) {
        gp += __shfl_xor(gp, off);
        sl += __shfl_xor(sl, off);
    }
    if (lane == 0) { wg[wid] = gp; wsl[wid] = sl; }
    __syncthreads();
    if (tid == 0) {
        float gold = 0.f; int seqs = 0;
        for (int w = 0; w < NWAVES; ++w) { gold += wg[w]; seqs += wsl[w]; }
        int tg0 = tags[b * TT];
        gold += start_trans[tg0] + em_b[tg0];
        int last_idx = seqs - 1;
        int tgl = tags[b * TT + last_idx];
        gold += end_trans[tgl];
        float seqf = fmaxf((float)seqs, 1.0f);
        out[b] = (sh_logden - gold) / seqf;
    }
}

extern "C" void kernel_launch(void* const* d_in, const int* in_sizes, int n_in,
                              void* d_out, int out_size, void* d_ws, size_t ws_size,
                              hipStream_t stream) {
    const float* emissions   = (const float*)d_in[0];
    const int*   tags        = (const int*)d_in[1];
    const int*   mask        = (const int*)d_in[2];
    const float* trans       = (const float*)d_in[3];
    const float* start_trans = (const float*)d_in[4];
    const float* end_trans   = (const float*)d_in[5];
    float* out = (float*)d_out;

    crf_kernel<<<BB, NTHREADS, 0, stream>>>(emissions, tags, mask, trans,
                                            start_trans, end_trans, out);
}

// Round 7
// 518.276 us; speedup vs baseline: 1.1519x; 1.1519x over previous
//
#include <hip/hip_runtime.h>

#define BB 128
#define TT 1024
#define VV 192
#define NTHREADS 256
#define NWAVES 4
#define LN2 0.69314718055994530942f

typedef int   intx8   __attribute__((ext_vector_type(8)));
typedef float floatx2 __attribute__((ext_vector_type(2)));
typedef float floatx4 __attribute__((ext_vector_type(4)));

__device__ __forceinline__ float bf8_to_f32(unsigned char h) {
    floatx2 v = __builtin_amdgcn_cvt_pk_f32_bf8((int)(unsigned int)h, false);
    return v.x;
}
__device__ __forceinline__ unsigned char f32_to_bf8(float f) {
    int pk = __builtin_amdgcn_cvt_pk_bf8_f32(f, f, 0, false);
    return (unsigned char)(pk & 0xff);
}
__device__ __forceinline__ unsigned char f32_to_fp8(float f) {
    int pk = __builtin_amdgcn_cvt_pk_fp8_f32(f, f, 0, false);
    return (unsigned char)(pk & 0xff);
}

// LDS-only barrier: does NOT drain vmcnt (global loads stay in flight)
#define LBAR() __asm__ volatile("s_waitcnt lgkmcnt(0)\n\ts_barrier" ::: "memory")

__launch_bounds__(NTHREADS, 1)
__global__ void crf_kernel(const float* __restrict__ emissions,
                           const int* __restrict__ tags,
                           const int* __restrict__ mask,
                           const float* __restrict__ trans,
                           const float* __restrict__ start_trans,
                           const float* __restrict__ end_trans,
                           float* __restrict__ out)
{
    const int b = blockIdx.x;
    const int tid = threadIdx.x;
    const int lane = tid & 63;
    const int wid = tid >> 6;        // 0..3
    const int quad = lane >> 4;      // 0..3
    const int col = lane & 15;       // 0..15

    // Q state in e5m2 bytes, double-buffered, K-padded to 256 (pad stays 0)
    __shared__ __align__(16) unsigned char qpad[2][256];
    __shared__ int smask[TT];
    __shared__ float wred[NWAVES];
    __shared__ float wg[NWAVES];
    __shared__ int   wsl[NWAVES];
    __shared__ float sh_logden;

    const float* em_b = emissions + (size_t)b * TT * VV;
    const int* mask_b = mask + b * TT;

    // this lane's epilogue column (quads 0..2 own one column; quad 3 dups quad 0)
    const int nl = wid * 48 + (quad < 3 ? quad : 0) * 16 + col;

    // ---- E fragments, e4m3, MX 16x16x128 B-operand: 2 K-tiles x 3 N-tiles ----
    // byte-slot mapping assumption: k = ktile*128 + quad*32 + j  (j = byte 0..31).
    // Any slot<->k permutation cancels (A packed with same mapping); k>=192 -> 0.
    intx8 ef[6];
    #pragma unroll
    for (int kt = 0; kt < 2; ++kt) {
        #pragma unroll
        for (int h = 0; h < 3; ++h) {
            const int n = wid * 48 + h * 16 + col;
            intx8 v;
            #pragma unroll
            for (int w = 0; w < 8; ++w) {
                unsigned int word = 0;
                #pragma unroll
                for (int by = 0; by < 4; ++by) {
                    int k = kt * 128 + quad * 32 + w * 4 + by;
                    float x = (k < VV) ? __expf(trans[k * VV + n]) : 0.f;
                    word |= (unsigned int)f32_to_fp8(x) << (8 * by);
                }
                v[w] = (int)word;
            }
            ef[kt * 3 + h] = v;
        }
    }

    // ---- zero both Q buffers (pad bytes 192..255 must stay 0 forever) ----
    for (int i = tid; i < 512; i += NTHREADS) ((unsigned char*)qpad)[i] = 0;

    // ---- preload mask into LDS ----
    for (int t = tid; t < TT; t += NTHREADS) smask[t] = mask_b[t];

    // ---- raw emission registers for this lane's column (exp applied lazily) ----
    float em0[8], em1[8];
    #pragma unroll
    for (int r = 0; r < 8; ++r) em0[r] = em_b[(size_t)r * VV + nl];
    #pragma unroll
    for (int r = 0; r < 8; ++r) em1[r] = em_b[(size_t)(8 + r) * VV + nl];

    // ---- init Q0 ----
    __syncthreads();   // zero-fill visible before Q0 write
    if (tid < VV) {
        float a0 = start_trans[tid] + em_b[tid];
        qpad[0][tid] = f32_to_bf8(fminf(__expf(a0), 28672.f));
    }
    float carry2 = 0.f;
    int cur = 0;
    __syncthreads();

    // one CRF step t: consumes qpad[cur]; emraw = raw em[t][nl]
    auto dostep = [&](int t, float emraw) {
        const unsigned char* qc = qpad[cur];
        const uint4* qp = (const uint4*)qc;
        uint4 w0 = qp[quad * 2];
        uint4 w1 = qp[quad * 2 + 1];
        uint4 w2 = qp[8 + quad * 2];
        uint4 w3 = qp[8 + quad * 2 + 1];
        float q0 = bf8_to_f32(qc[0]);
        int mk = smask[t];
        unsigned char prevb = 0;
        if (!mk) prevb = qc[nl];          // uniform branch; skipped when mask=1

        intx8 A0 = (intx8){(int)w0.x, (int)w0.y, (int)w0.z, (int)w0.w,
                           (int)w1.x, (int)w1.y, (int)w1.z, (int)w1.w};
        intx8 A1 = (intx8){(int)w2.x, (int)w2.y, (int)w2.z, (int)w2.w,
                           (int)w3.x, (int)w3.y, (int)w3.z, (int)w3.w};

        floatx4 acc[3];
        #pragma unroll
        for (int h = 0; h < 3; ++h) acc[h] = (floatx4){0.f, 0.f, 0.f, 0.f};
        #pragma unroll
        for (int h = 0; h < 3; ++h)
            acc[h] = __builtin_amdgcn_mfma_scale_f32_16x16x128_f8f6f4(
                         A0, ef[h], acc[h], 1, 0, 0, 0x7f7f7f7f, 0, 0x7f7f7f7f);
        #pragma unroll
        for (int h = 0; h < 3; ++h)
            acc[h] = __builtin_amdgcn_mfma_scale_f32_16x16x128_f8f6f4(
                         A1, ef[3 + h], acc[h], 1, 0, 0, 0x7f7f7f7f, 0, 0x7f7f7f7f);

        float r = __builtin_amdgcn_rcpf(q0);
        carry2 += mk ? __log2f(q0) : 0.f;

        if (quad < 3) {
            float pe = __expf(emraw);
            float qn = fminf(acc[quad][0] * pe * r, 28672.f);
            unsigned char nb = mk ? f32_to_bf8(qn) : prevb;
            qpad[cur ^ 1][nl] = nb;
        }
        LBAR();
        cur ^= 1;
    };

    // ---- main loop: 16-step bodies; em0/em1 refilled raw right after last use ----
    for (int t0 = 0; t0 < TT; t0 += 16) {
        if (t0 > 0) dostep(t0 + 0, em0[0]);
        dostep(t0 + 1, em0[1]);
        dostep(t0 + 2, em0[2]);
        dostep(t0 + 3, em0[3]);
        dostep(t0 + 4, em0[4]);
        dostep(t0 + 5, em0[5]);
        dostep(t0 + 6, em0[6]);
        dostep(t0 + 7, em0[7]);
        // refill em0 <- raw rows [t0+16, t0+24); first use 9 steps away
        {
            #pragma unroll
            for (int r = 0; r < 8; ++r) {
                int rr = t0 + 16 + r; rr = rr < TT ? rr : TT - 1;
                em0[r] = em_b[(size_t)rr * VV + nl];
            }
        }
        dostep(t0 + 8,  em1[0]);
        dostep(t0 + 9,  em1[1]);
        dostep(t0 + 10, em1[2]);
        dostep(t0 + 11, em1[3]);
        dostep(t0 + 12, em1[4]);
        dostep(t0 + 13, em1[5]);
        dostep(t0 + 14, em1[6]);
        dostep(t0 + 15, em1[7]);
        // refill em1 <- raw rows [t0+24, t0+32); first use 9 steps away
        {
            #pragma unroll
            for (int r = 0; r < 8; ++r) {
                int rr = t0 + 24 + r; rr = rr < TT ? rr : TT - 1;
                em1[r] = em_b[(size_t)rr * VV + nl];
            }
        }
    }

    // ---- final lse: logden = ln2*carry2 + log(sum_j Q[j]*exp(end[j])) ----
    float v = 0.f;
    if (tid < VV) v = bf8_to_f32(qpad[cur][tid]) * __expf(end_trans[tid]);
    #pragma unroll
    for (int off = 1; off < 64; off <<= 1)
        v += __shfl_xor(v, off);
    if (lane == 0) wred[wid] = v;
    __syncthreads();
    if (tid == 0) {
        float ssum = 0.f;
        for (int w = 0; w < NWAVES; ++w) ssum += wred[w];
        sh_logden = LN2 * carry2 + __logf(ssum + 1e-8f);
    }

    // ---- gold score + seq_len (strided over t) ----
    float gp = 0.f;
    int sl = 0;
    for (int t = tid; t < TT; t += NTHREADS) {
        sl += smask[t];
        if (t >= 1) {
            int tg  = tags[b * TT + t];
            int tgp = tags[b * TT + t - 1];
            float term = em_b[(size_t)t * VV + tg] + trans[tgp * VV + tg];
            gp += smask[t] ? term : 0.f;
        }
    }
    #pragma unroll
    for (int off = 1; off < 64; off <<= 1) {
        gp += __shfl_xor(gp, off);
        sl += __shfl_xor(sl, off);
    }
    if (lane == 0) { wg[wid] = gp; wsl[wid] = sl; }
    __syncthreads();
    if (tid == 0) {
        float gold = 0.f; int seqs = 0;
        for (int w = 0; w < NWAVES; ++w) { gold += wg[w]; seqs += wsl[w]; }
        int tg0 = tags[b * TT];
        gold += start_trans[tg0] + em_b[tg0];
        int last_idx = seqs - 1;
        int tgl = tags[b * TT + last_idx];
        gold += end_trans[tgl];
        float seqf = fmaxf((float)seqs, 1.0f);
        out[b] = (sh_logden - gold) / seqf;
    }
}

extern "C" void kernel_launch(void* const* d_in, const int* in_sizes, int n_in,
                              void* d_out, int out_size, void* d_ws, size_t ws_size,
                              hipStream_t stream) {
    const float* emissions   = (const float*)d_in[0];
    const int*   tags        = (const int*)d_in[1];
    const int*   mask        = (const int*)d_in[2];
    const float* trans       = (const float*)d_in[3];
    const float* start_trans = (const float*)d_in[4];
    const float* end_trans   = (const float*)d_in[5];
    float* out = (float*)d_out;

    crf_kernel<<<BB, NTHREADS, 0, stream>>>(emissions, tags, mask, trans,
                                            start_trans, end_trans, out);
}